// Round 5
// baseline (451.961 us; speedup 1.0000x reference)
//
#include <hip/hip_runtime.h>
#include <hip/hip_bf16.h>
#include <hip/hip_fp16.h>

// FISM forward, MI355X — round 5.
// R4 bug: u64 repack left bits 32-63 uninitialized before OR ("w |= hi<<32"
// on a w whose upper half was never written) -> corrupted fp16 -> NaN on
// first launch. Fixed: build w from two fully-initialized u32.
// R4's untested hypothesis stands: agent-scope (sc1 write-through) stores in
// the convert pass + agent release fence make the fp16 tables visible to
// gather waves on other XCDs under graph replay (normal dispatch's L2
// writeback between kernels appears to be elided by the graph barrier).

constexpr int B_SZ   = 16384;
constexpr int K_NB   = 50;
constexpr int NNEG   = 20;
constexpr int D_DIM  = 128;
constexpr int N_ITEMS = 100000;

// ---------------- pass 1: fp32 -> fp16 table conversion ----------------
__global__ __launch_bounds__(256) void convert_tables(
    const float4* __restrict__ P4,   // [N_ITEMS*D/4]
    const float4* __restrict__ Q4,
    unsigned long long* __restrict__ Ph2,   // fp16 bits, 4 halves per u64
    unsigned long long* __restrict__ Qh2)
{
    const size_t nPer  = (size_t)N_ITEMS * D_DIM / 4;   // float4 count / table
    const size_t total = 2 * nPer;
    const size_t stride = (size_t)gridDim.x * blockDim.x;
    for (size_t i = (size_t)blockIdx.x * blockDim.x + threadIdx.x;
         i < total; i += stride) {
        const bool isP = (i < nPer);
        const size_t j = isP ? i : i - nPer;
        const float4 v = isP ? P4[j] : Q4[j];
        const __half2 h01 = __floats2half2_rn(v.x, v.y);
        const __half2 h23 = __floats2half2_rn(v.z, v.w);
        unsigned int lo, hi;
        __builtin_memcpy(&lo, &h01, 4);
        __builtin_memcpy(&hi, &h23, 4);
        const unsigned long long w =
            (unsigned long long)lo | ((unsigned long long)hi << 32);
        // device-scope store: write-through past this XCD's L2 (sc1) so the
        // consumer kernel sees it regardless of graph barrier cache policy.
        __hip_atomic_store(isP ? (Ph2 + j) : (Qh2 + j), w,
                           __ATOMIC_RELAXED, __HIP_MEMORY_SCOPE_AGENT);
    }
    __syncthreads();                       // all block stores issued
    if (threadIdx.x == 0)
        __builtin_amdgcn_fence(__ATOMIC_RELEASE, "agent");  // L2 writeback
}

// ---------------- pass 2: gather + dot (fp16 tables) ----------------
__global__ __launch_bounds__(256) void fism_fwd_h(
    const int* __restrict__ I,
    const int* __restrict__ U,
    const int* __restrict__ I_neg,
    const int* __restrict__ I_U,
    const int* __restrict__ N_U,
    const int* __restrict__ I_in_I_U,
    const __half* __restrict__ Ph,   // [N_ITEMS, D] fp16
    const __half* __restrict__ Qh,
    const float* __restrict__ b_u,
    const float* __restrict__ b_i,
    float* __restrict__ r,
    float* __restrict__ r_neg)
{
    const int wave = (blockIdx.x * blockDim.x + threadIdx.x) >> 6;
    if (wave >= B_SZ) return;
    const int lane = threadIdx.x & 63;
    const int sl   = lane & 31;   // owns dims [4*sl .. 4*sl+3]
    const int half = lane >> 5;   // which of 2 rows this half-wave loads
    const int b    = wave;

    // ---- stage indices (one coalesced load per table) ----
    int my_nbr = 0, my_neg = 0;
    if (lane < K_NB)  my_nbr = I_U[b * K_NB + lane];
    if (lane < NNEG)  my_neg = I_neg[b * NNEG + lane];
    const int   ii  = I[b];
    const int   uu  = U[b];
    const float ind = (float)I_in_I_U[b];
    const float nuf = (float)N_U[b];

    const float bu     = b_u[uu];
    const float bi_pos = b_i[ii];
    float my_bneg = 0.f;
    if (lane < NNEG) my_bneg = b_i[my_neg];

    // early loads: self P row + positive Q row (256 B each, fp16)
    const uint2 wps = ((const uint2*)(Ph + (size_t)ii * D_DIM))[sl];
    const uint2 wqp = ((const uint2*)(Qh + (size_t)ii * D_DIM))[sl];

    // ---- P-sum: 2 rows per wave-load, 25 iterations ----
    float4 acc = {0.f, 0.f, 0.f, 0.f};
    #pragma unroll 5
    for (int k = 0; k < K_NB / 2; ++k) {
        const int item = __shfl(my_nbr, 2 * k + half, 64);
        const uint2 w = ((const uint2*)(Ph + (size_t)item * D_DIM))[sl];
        __half2 h01, h23;
        __builtin_memcpy(&h01, &w.x, 4);
        __builtin_memcpy(&h23, &w.y, 4);
        const float2 f01 = __half22float2(h01);
        const float2 f23 = __half22float2(h23);
        acc.x += f01.x; acc.y += f01.y; acc.z += f23.x; acc.w += f23.y;
    }
    acc.x += __shfl_xor(acc.x, 32, 64);
    acc.y += __shfl_xor(acc.y, 32, 64);
    acc.z += __shfl_xor(acc.z, 32, 64);
    acc.w += __shfl_xor(acc.w, 32, 64);

    const float inv = 1.0f / fmaxf(nuf - ind, 1.0f);   // ALPHA = 1
    {
        __half2 h01, h23;
        __builtin_memcpy(&h01, &wps.x, 4);
        __builtin_memcpy(&h23, &wps.y, 4);
        const float2 f01 = __half22float2(h01);
        const float2 f23 = __half22float2(h23);
        acc.x = (acc.x - f01.x * ind) * inv;
        acc.y = (acc.y - f01.y * ind) * inv;
        acc.z = (acc.z - f23.x * ind) * inv;
        acc.w = (acc.w - f23.y * ind) * inv;
    }

    // ---- positive dot ----
    {
        __half2 h01, h23;
        __builtin_memcpy(&h01, &wqp.x, 4);
        __builtin_memcpy(&h23, &wqp.y, 4);
        const float2 f01 = __half22float2(h01);
        const float2 f23 = __half22float2(h23);
        float dot = acc.x * f01.x + acc.y * f01.y + acc.z * f23.x + acc.w * f23.y;
        #pragma unroll
        for (int m = 16; m > 0; m >>= 1)
            dot += __shfl_xor(dot, m, 64);
        if (lane == 0) r[b] = bu + bi_pos + dot;
    }

    // ---- negatives: 2 per iteration ----
    #pragma unroll 5
    for (int t = 0; t < NNEG / 2; ++t) {
        const int n    = 2 * t + half;
        const int item = __shfl(my_neg,  n, 64);
        const float bn = __shfl(my_bneg, n, 64);
        const uint2 w = ((const uint2*)(Qh + (size_t)item * D_DIM))[sl];
        __half2 h01, h23;
        __builtin_memcpy(&h01, &w.x, 4);
        __builtin_memcpy(&h23, &w.y, 4);
        const float2 f01 = __half22float2(h01);
        const float2 f23 = __half22float2(h23);
        float d = acc.x * f01.x + acc.y * f01.y + acc.z * f23.x + acc.w * f23.y;
        #pragma unroll
        for (int m = 16; m > 0; m >>= 1)
            d += __shfl_xor(d, m, 64);
        if (sl == 0) r_neg[b * NNEG + n] = bu + bn + d;  // lanes 0 and 32
    }
}

// ---------------- fallback: R2 fp32 kernel (if ws too small) ----------------
__global__ __launch_bounds__(256) void fism_fwd_f32(
    const int* __restrict__ I, const int* __restrict__ U,
    const int* __restrict__ I_neg, const int* __restrict__ I_U,
    const int* __restrict__ N_U, const int* __restrict__ I_in_I_U,
    const float* __restrict__ P, const float* __restrict__ Q,
    const float* __restrict__ b_u, const float* __restrict__ b_i,
    float* __restrict__ r, float* __restrict__ r_neg)
{
    const int wave = (blockIdx.x * blockDim.x + threadIdx.x) >> 6;
    if (wave >= B_SZ) return;
    const int lane = threadIdx.x & 63;
    const int sl   = lane & 31;
    const int half = lane >> 5;
    const int b    = wave;

    int my_nbr = 0, my_neg = 0;
    if (lane < K_NB)  my_nbr = I_U[b * K_NB + lane];
    if (lane < NNEG)  my_neg = I_neg[b * NNEG + lane];
    const int   ii  = I[b];
    const int   uu  = U[b];
    const float ind = (float)I_in_I_U[b];
    const float nuf = (float)N_U[b];
    const float bu     = b_u[uu];
    const float bi_pos = b_i[ii];
    float my_bneg = 0.f;
    if (lane < NNEG) my_bneg = b_i[my_neg];

    const float4 ps = ((const float4*)(P + (size_t)ii * D_DIM))[sl];
    const float4 qp = ((const float4*)(Q + (size_t)ii * D_DIM))[sl];

    float4 acc = {0.f, 0.f, 0.f, 0.f};
    #pragma unroll 5
    for (int k = 0; k < K_NB / 2; ++k) {
        const int item = __shfl(my_nbr, 2 * k + half, 64);
        const float4 v = ((const float4*)(P + (size_t)item * D_DIM))[sl];
        acc.x += v.x; acc.y += v.y; acc.z += v.z; acc.w += v.w;
    }
    acc.x += __shfl_xor(acc.x, 32, 64);
    acc.y += __shfl_xor(acc.y, 32, 64);
    acc.z += __shfl_xor(acc.z, 32, 64);
    acc.w += __shfl_xor(acc.w, 32, 64);

    const float inv = 1.0f / fmaxf(nuf - ind, 1.0f);
    float4 pctx;
    pctx.x = (acc.x - ps.x * ind) * inv;
    pctx.y = (acc.y - ps.y * ind) * inv;
    pctx.z = (acc.z - ps.z * ind) * inv;
    pctx.w = (acc.w - ps.w * ind) * inv;

    {
        float dot = pctx.x * qp.x + pctx.y * qp.y + pctx.z * qp.z + pctx.w * qp.w;
        #pragma unroll
        for (int m = 16; m > 0; m >>= 1) dot += __shfl_xor(dot, m, 64);
        if (lane == 0) r[b] = bu + bi_pos + dot;
    }
    #pragma unroll 5
    for (int t = 0; t < NNEG / 2; ++t) {
        const int n    = 2 * t + half;
        const int item = __shfl(my_neg,  n, 64);
        const float bn = __shfl(my_bneg, n, 64);
        const float4 qv = ((const float4*)(Q + (size_t)item * D_DIM))[sl];
        float d = pctx.x * qv.x + pctx.y * qv.y + pctx.z * qv.z + pctx.w * qv.w;
        #pragma unroll
        for (int m = 16; m > 0; m >>= 1) d += __shfl_xor(d, m, 64);
        if (sl == 0) r_neg[b * NNEG + n] = bu + bn + d;
    }
}

extern "C" void kernel_launch(void* const* d_in, const int* in_sizes, int n_in,
                              void* d_out, int out_size, void* d_ws, size_t ws_size,
                              hipStream_t stream) {
    const int*   I        = (const int*)d_in[0];
    const int*   U        = (const int*)d_in[1];
    const int*   I_neg    = (const int*)d_in[2];
    const int*   I_U      = (const int*)d_in[3];
    const int*   N_U      = (const int*)d_in[4];
    const int*   I_in_I_U = (const int*)d_in[5];
    const float* P_emb    = (const float*)d_in[6];
    const float* Q_emb    = (const float*)d_in[7];
    const float* b_u      = (const float*)d_in[8];
    const float* b_i      = (const float*)d_in[9];

    float* r     = (float*)d_out;
    float* r_neg = (float*)d_out + B_SZ;

    const size_t tbl_elems = (size_t)N_ITEMS * D_DIM;
    const size_t need = 2 * tbl_elems * sizeof(__half);   // 51.2 MB

    if (ws_size >= need) {
        __half* Ph = (__half*)d_ws;
        __half* Qh = Ph + tbl_elems;
        convert_tables<<<8192, 256, 0, stream>>>(
            (const float4*)P_emb, (const float4*)Q_emb,
            (unsigned long long*)Ph, (unsigned long long*)Qh);
        fism_fwd_h<<<B_SZ / 4, 256, 0, stream>>>(
            I, U, I_neg, I_U, N_U, I_in_I_U, Ph, Qh, b_u, b_i, r, r_neg);
    } else {
        fism_fwd_f32<<<B_SZ / 4, 256, 0, stream>>>(
            I, U, I_neg, I_U, N_U, I_in_I_U, P_emb, Q_emb, b_u, b_i, r, r_neg);
    }
}

// Round 6
// 281.111 us; speedup vs baseline: 1.6078x; 1.6078x over previous
//
#include <hip/hip_runtime.h>
#include <hip/hip_bf16.h>
#include <hip/hip_fp16.h>

// FISM forward, MI355X — round 6.
// R5 passed (incl. graph-replay post-timing check) proving the coherence
// model: producer must push fp16 tables past its XCD L2 before the gather
// kernel; reader-side kernel-begin invalidates work fine under replay.
// But 8B sc1 write-through stores ran at 332 GB/s (308 us). Fix: plain
// cached stores (full L2 write-combining, 16B dwordx4) + ONE agent-release
// fence per block (s_waitcnt vmcnt(0) + buffer_wbl2 sc1) after
// __syncthreads() — each block's dirty lines are written back by its own
// fence before kernel end. Gather kernel unchanged from R5.

constexpr int B_SZ   = 16384;
constexpr int K_NB   = 50;
constexpr int NNEG   = 20;
constexpr int D_DIM  = 128;
constexpr int N_ITEMS = 100000;

__device__ __forceinline__ unsigned int pack_h2(float a, float b) {
    const __half2 h = __floats2half2_rn(a, b);
    unsigned int u;
    __builtin_memcpy(&u, &h, 4);
    return u;
}

// ---------------- pass 1: fp32 -> fp16 table conversion ----------------
// Each iteration: 32 B load (2x float4) -> 16 B store (uint4 of 8 halves).
__global__ __launch_bounds__(256) void convert_tables(
    const float4* __restrict__ P4,   // [N_ITEMS*D/4]
    const float4* __restrict__ Q4,
    uint4* __restrict__ Ph4,         // [N_ITEMS*D/8] fp16 bits
    uint4* __restrict__ Qh4)
{
    const size_t nPer  = (size_t)N_ITEMS * D_DIM / 8;   // uint4 count / table
    const size_t total = 2 * nPer;
    const size_t stride = (size_t)gridDim.x * blockDim.x;
    for (size_t i = (size_t)blockIdx.x * blockDim.x + threadIdx.x;
         i < total; i += stride) {
        const bool isP = (i < nPer);
        const size_t j = isP ? i : i - nPer;
        const float4* src = (isP ? P4 : Q4) + 2 * j;
        const float4 a = src[0];
        const float4 c = src[1];
        uint4 w;
        w.x = pack_h2(a.x, a.y);
        w.y = pack_h2(a.z, a.w);
        w.z = pack_h2(c.x, c.y);
        w.w = pack_h2(c.z, c.w);
        (isP ? Ph4 : Qh4)[j] = w;           // plain cached store -> L2
    }
    __syncthreads();   // compiler emits s_waitcnt vmcnt(0) before s_barrier
    if (threadIdx.x == 0)
        __builtin_amdgcn_fence(__ATOMIC_RELEASE, "agent");  // buffer_wbl2 sc1
}

// ---------------- pass 2: gather + dot (fp16 tables) ----------------
__global__ __launch_bounds__(256) void fism_fwd_h(
    const int* __restrict__ I,
    const int* __restrict__ U,
    const int* __restrict__ I_neg,
    const int* __restrict__ I_U,
    const int* __restrict__ N_U,
    const int* __restrict__ I_in_I_U,
    const __half* __restrict__ Ph,   // [N_ITEMS, D] fp16
    const __half* __restrict__ Qh,
    const float* __restrict__ b_u,
    const float* __restrict__ b_i,
    float* __restrict__ r,
    float* __restrict__ r_neg)
{
    const int wave = (blockIdx.x * blockDim.x + threadIdx.x) >> 6;
    if (wave >= B_SZ) return;
    const int lane = threadIdx.x & 63;
    const int sl   = lane & 31;   // owns dims [4*sl .. 4*sl+3]
    const int half = lane >> 5;   // which of 2 rows this half-wave loads
    const int b    = wave;

    // ---- stage indices (one coalesced load per table) ----
    int my_nbr = 0, my_neg = 0;
    if (lane < K_NB)  my_nbr = I_U[b * K_NB + lane];
    if (lane < NNEG)  my_neg = I_neg[b * NNEG + lane];
    const int   ii  = I[b];
    const int   uu  = U[b];
    const float ind = (float)I_in_I_U[b];
    const float nuf = (float)N_U[b];

    const float bu     = b_u[uu];
    const float bi_pos = b_i[ii];
    float my_bneg = 0.f;
    if (lane < NNEG) my_bneg = b_i[my_neg];

    // early loads: self P row + positive Q row (256 B each, fp16)
    const uint2 wps = ((const uint2*)(Ph + (size_t)ii * D_DIM))[sl];
    const uint2 wqp = ((const uint2*)(Qh + (size_t)ii * D_DIM))[sl];

    // ---- P-sum: 2 rows per wave-load, 25 iterations ----
    float4 acc = {0.f, 0.f, 0.f, 0.f};
    #pragma unroll 5
    for (int k = 0; k < K_NB / 2; ++k) {
        const int item = __shfl(my_nbr, 2 * k + half, 64);
        const uint2 w = ((const uint2*)(Ph + (size_t)item * D_DIM))[sl];
        __half2 h01, h23;
        __builtin_memcpy(&h01, &w.x, 4);
        __builtin_memcpy(&h23, &w.y, 4);
        const float2 f01 = __half22float2(h01);
        const float2 f23 = __half22float2(h23);
        acc.x += f01.x; acc.y += f01.y; acc.z += f23.x; acc.w += f23.y;
    }
    acc.x += __shfl_xor(acc.x, 32, 64);
    acc.y += __shfl_xor(acc.y, 32, 64);
    acc.z += __shfl_xor(acc.z, 32, 64);
    acc.w += __shfl_xor(acc.w, 32, 64);

    const float inv = 1.0f / fmaxf(nuf - ind, 1.0f);   // ALPHA = 1
    {
        __half2 h01, h23;
        __builtin_memcpy(&h01, &wps.x, 4);
        __builtin_memcpy(&h23, &wps.y, 4);
        const float2 f01 = __half22float2(h01);
        const float2 f23 = __half22float2(h23);
        acc.x = (acc.x - f01.x * ind) * inv;
        acc.y = (acc.y - f01.y * ind) * inv;
        acc.z = (acc.z - f23.x * ind) * inv;
        acc.w = (acc.w - f23.y * ind) * inv;
    }

    // ---- positive dot ----
    {
        __half2 h01, h23;
        __builtin_memcpy(&h01, &wqp.x, 4);
        __builtin_memcpy(&h23, &wqp.y, 4);
        const float2 f01 = __half22float2(h01);
        const float2 f23 = __half22float2(h23);
        float dot = acc.x * f01.x + acc.y * f01.y + acc.z * f23.x + acc.w * f23.y;
        #pragma unroll
        for (int m = 16; m > 0; m >>= 1)
            dot += __shfl_xor(dot, m, 64);
        if (lane == 0) r[b] = bu + bi_pos + dot;
    }

    // ---- negatives: 2 per iteration ----
    #pragma unroll 5
    for (int t = 0; t < NNEG / 2; ++t) {
        const int n    = 2 * t + half;
        const int item = __shfl(my_neg,  n, 64);
        const float bn = __shfl(my_bneg, n, 64);
        const uint2 w = ((const uint2*)(Qh + (size_t)item * D_DIM))[sl];
        __half2 h01, h23;
        __builtin_memcpy(&h01, &w.x, 4);
        __builtin_memcpy(&h23, &w.y, 4);
        const float2 f01 = __half22float2(h01);
        const float2 f23 = __half22float2(h23);
        float d = acc.x * f01.x + acc.y * f01.y + acc.z * f23.x + acc.w * f23.y;
        #pragma unroll
        for (int m = 16; m > 0; m >>= 1)
            d += __shfl_xor(d, m, 64);
        if (sl == 0) r_neg[b * NNEG + n] = bu + bn + d;  // lanes 0 and 32
    }
}

// ---------------- fallback: R2 fp32 kernel (if ws too small) ----------------
__global__ __launch_bounds__(256) void fism_fwd_f32(
    const int* __restrict__ I, const int* __restrict__ U,
    const int* __restrict__ I_neg, const int* __restrict__ I_U,
    const int* __restrict__ N_U, const int* __restrict__ I_in_I_U,
    const float* __restrict__ P, const float* __restrict__ Q,
    const float* __restrict__ b_u, const float* __restrict__ b_i,
    float* __restrict__ r, float* __restrict__ r_neg)
{
    const int wave = (blockIdx.x * blockDim.x + threadIdx.x) >> 6;
    if (wave >= B_SZ) return;
    const int lane = threadIdx.x & 63;
    const int sl   = lane & 31;
    const int half = lane >> 5;
    const int b    = wave;

    int my_nbr = 0, my_neg = 0;
    if (lane < K_NB)  my_nbr = I_U[b * K_NB + lane];
    if (lane < NNEG)  my_neg = I_neg[b * NNEG + lane];
    const int   ii  = I[b];
    const int   uu  = U[b];
    const float ind = (float)I_in_I_U[b];
    const float nuf = (float)N_U[b];
    const float bu     = b_u[uu];
    const float bi_pos = b_i[ii];
    float my_bneg = 0.f;
    if (lane < NNEG) my_bneg = b_i[my_neg];

    const float4 ps = ((const float4*)(P + (size_t)ii * D_DIM))[sl];
    const float4 qp = ((const float4*)(Q + (size_t)ii * D_DIM))[sl];

    float4 acc = {0.f, 0.f, 0.f, 0.f};
    #pragma unroll 5
    for (int k = 0; k < K_NB / 2; ++k) {
        const int item = __shfl(my_nbr, 2 * k + half, 64);
        const float4 v = ((const float4*)(P + (size_t)item * D_DIM))[sl];
        acc.x += v.x; acc.y += v.y; acc.z += v.z; acc.w += v.w;
    }
    acc.x += __shfl_xor(acc.x, 32, 64);
    acc.y += __shfl_xor(acc.y, 32, 64);
    acc.z += __shfl_xor(acc.z, 32, 64);
    acc.w += __shfl_xor(acc.w, 32, 64);

    const float inv = 1.0f / fmaxf(nuf - ind, 1.0f);
    float4 pctx;
    pctx.x = (acc.x - ps.x * ind) * inv;
    pctx.y = (acc.y - ps.y * ind) * inv;
    pctx.z = (acc.z - ps.z * ind) * inv;
    pctx.w = (acc.w - ps.w * ind) * inv;

    {
        float dot = pctx.x * qp.x + pctx.y * qp.y + pctx.z * qp.z + pctx.w * qp.w;
        #pragma unroll
        for (int m = 16; m > 0; m >>= 1) dot += __shfl_xor(dot, m, 64);
        if (lane == 0) r[b] = bu + bi_pos + dot;
    }
    #pragma unroll 5
    for (int t = 0; t < NNEG / 2; ++t) {
        const int n    = 2 * t + half;
        const int item = __shfl(my_neg,  n, 64);
        const float bn = __shfl(my_bneg, n, 64);
        const float4 qv = ((const float4*)(Q + (size_t)item * D_DIM))[sl];
        float d = pctx.x * qv.x + pctx.y * qv.y + pctx.z * qv.z + pctx.w * qv.w;
        #pragma unroll
        for (int m = 16; m > 0; m >>= 1) d += __shfl_xor(d, m, 64);
        if (sl == 0) r_neg[b * NNEG + n] = bu + bn + d;
    }
}

extern "C" void kernel_launch(void* const* d_in, const int* in_sizes, int n_in,
                              void* d_out, int out_size, void* d_ws, size_t ws_size,
                              hipStream_t stream) {
    const int*   I        = (const int*)d_in[0];
    const int*   U        = (const int*)d_in[1];
    const int*   I_neg    = (const int*)d_in[2];
    const int*   I_U      = (const int*)d_in[3];
    const int*   N_U      = (const int*)d_in[4];
    const int*   I_in_I_U = (const int*)d_in[5];
    const float* P_emb    = (const float*)d_in[6];
    const float* Q_emb    = (const float*)d_in[7];
    const float* b_u      = (const float*)d_in[8];
    const float* b_i      = (const float*)d_in[9];

    float* r     = (float*)d_out;
    float* r_neg = (float*)d_out + B_SZ;

    const size_t tbl_elems = (size_t)N_ITEMS * D_DIM;
    const size_t need = 2 * tbl_elems * sizeof(__half);   // 51.2 MB

    if (ws_size >= need) {
        __half* Ph = (__half*)d_ws;
        __half* Qh = Ph + tbl_elems;
        convert_tables<<<2048, 256, 0, stream>>>(
            (const float4*)P_emb, (const float4*)Q_emb,
            (uint4*)Ph, (uint4*)Qh);
        fism_fwd_h<<<B_SZ / 4, 256, 0, stream>>>(
            I, U, I_neg, I_U, N_U, I_in_I_U, Ph, Qh, b_u, b_i, r, r_neg);
    } else {
        fism_fwd_f32<<<B_SZ / 4, 256, 0, stream>>>(
            I, U, I_neg, I_U, N_U, I_in_I_U, P_emb, Q_emb, b_u, b_i, r, r_neg);
    }
}